// Round 7
// baseline (339.849 us; speedup 1.0000x reference)
//
#include <hip/hip_runtime.h>
#include <cstdint>

// ---------------------------------------------------------------------------
// Attention (Luong general): out = softmax(dec @ (enc@W)^T) @ enc
// B=8, S_enc=S_dec=2048, H=512, fp32 in/out.
//
// bf16 MFMA; split-precision (hi+lo bf16, 3-term) for the two matmuls feeding
// softmax; plain bf16 for PV.
// Round 9: TRUE T4 vmcnt ladder in the logits GEMM -- every round so far
// still had a drain-to-zero vmcnt(0) inside the K-loop (the catalog's #1
// anti-pattern). Now: staging spread P0-P3 (Ah',Bh',Al',Bl', 2 loads each),
// counted waits P1-end vmcnt(6) / P3-end vmcnt(8) / P5-end vmcnt(4) derived
// from a per-wave outstanding ledger; every wait targets loads >=4 phases
// old; NO vmcnt(0) in the main loop. Barriers propagate per-wave guarantees.
// ---------------------------------------------------------------------------

#define DEVINL __device__ __forceinline__

typedef __attribute__((ext_vector_type(8))) short short8;
typedef __attribute__((ext_vector_type(4))) float f32x4;

DEVINL short f2bf(float x) {
    union { float f; uint32_t u; } v; v.f = x;
    uint32_t r = v.u + 0x7FFFu + ((v.u >> 16) & 1u);   // RNE
    return (short)(r >> 16);
}
DEVINL float bf2f(short h) {
    union { uint32_t u; float f; } v; v.u = ((uint32_t)(uint16_t)h) << 16;
    return v.f;
}

DEVINL void gload_lds16(const void* g, void* l) {
    __builtin_amdgcn_global_load_lds(
        (const __attribute__((address_space(1))) char*)g,
        (__attribute__((address_space(3))) char*)l, 16, 0, 0);
}

// ---------------------------------------------------------------------------
// split fp32 -> (hi, lo) bf16 arrays.  8 elems/thread, exact-cover grids.
// ---------------------------------------------------------------------------
__global__ __launch_bounds__(256)
void split_kernel(const float* __restrict__ x, short* __restrict__ hi,
                  short* __restrict__ lo)
{
    long i = ((long)blockIdx.x * 256 + threadIdx.x) * 8;
    f32x4 a = *(const f32x4*)(x + i);
    f32x4 b = *(const f32x4*)(x + i + 4);
    short8 h, l;
#pragma unroll
    for (int j = 0; j < 4; j++) {
        short ha = f2bf(a[j]); h[j] = ha;     l[j] = f2bf(a[j] - bf2f(ha));
        short hb = f2bf(b[j]); h[4 + j] = hb; l[4 + j] = f2bf(b[j] - bf2f(hb));
    }
    *(short8*)(hi + i) = h;
    *(short8*)(lo + i) = l;
}

// W[512k][512n] -> Wt_hi/lo[n][k]
__global__ __launch_bounds__(256)
void split_w_kernel(const float* __restrict__ w, short* __restrict__ wth,
                    short* __restrict__ wtl)
{
    int idx = blockIdx.x * 256 + threadIdx.x;   // k*512 + n
    int k = idx >> 9, n = idx & 511;
    float v = w[idx];
    short h = f2bf(v);
    wth[(long)n * 512 + k] = h;
    wtl[(long)n * 512 + k] = f2bf(v - bf2f(h));
}

// Fused: enc[b][s][e] fp32 -> enc_hi/enc_lo [b][s][e] bf16 + enc_t[b][e][s]
// bf16 (PV B-operand).  Reads enc exactly once.
__global__ __launch_bounds__(256)
void split_transpose_kernel(const float* __restrict__ x, short* __restrict__ hi,
                            short* __restrict__ lo, short* __restrict__ xt)
{
    __shared__ short tile[32][33];
    const int b  = blockIdx.z;
    const int s0 = blockIdx.x * 32;
    const int e0 = blockIdx.y * 32;
    const float* px = x + (long)b * 2048 * 512;
    short* ph = hi + (long)b * 2048 * 512;
    short* pl = lo + (long)b * 2048 * 512;
    short* pt = xt + (long)b * 512 * 2048;
    const int tx = threadIdx.x & 31;
    const int ty = threadIdx.x >> 5;   // 0..7
#pragma unroll
    for (int r = 0; r < 32; r += 8) {
        long idx = (long)(s0 + ty + r) * 512 + e0 + tx;
        float v = px[idx];
        short h = f2bf(v);
        ph[idx] = h;
        pl[idx] = f2bf(v - bf2f(h));
        tile[ty + r][tx] = h;
    }
    __syncthreads();
#pragma unroll
    for (int r = 0; r < 32; r += 8)
        pt[(long)(e0 + ty + r) * 2048 + s0 + tx] = tile[tx][ty + r];
}

// ---------------------------------------------------------------------------
// gemm_bt: C[m][n] = sum_k A[m][k]*B[n][k]  (both operands K-contiguous).
// 128x128 tile, BK=32, 4 waves (2x2 of 64x64), 16x16x32 bf16 MFMA.
// (kept for the enc@W projection and the PV matmul)
// ---------------------------------------------------------------------------
template<int NTERMS, bool SPLIT_OUT>
__global__ __launch_bounds__(256, 2)
void gemm_bt(const short* __restrict__ Ah, const short* __restrict__ Al,
             const short* __restrict__ Bh, const short* __restrict__ Bl,
             float* __restrict__ C, short* __restrict__ Ch, short* __restrict__ Cl,
             int K, int lda, int ldb, int ldc,
             long sA, long sB, long sC)
{
    extern __shared__ char smem_raw[];
    constexpr int OPS = (NTERMS == 3) ? 4 : 2;     // operand planes per set
    constexpr int SET = 128 * 32 * OPS;            // shorts per buffer set
    short* smem = (short*)smem_raw;                // 2 sets

    const int tid  = threadIdx.x;
    const int wave = tid >> 6;
    const int lane = tid & 63;
    const int quad = lane >> 4;
    const int l16  = lane & 15;
    const int wm   = (wave >> 1) * 64;
    const int wn   = (wave & 1) * 64;

    const long tile_m = (long)blockIdx.y * 128;
    const long tile_n = (long)blockIdx.x * 128;
    const int  bz     = blockIdx.z;

    const short* pAh = Ah + (long)bz * sA;
    const short* pBh = Bh + (long)bz * sB;
    const short* pAl = (NTERMS == 3) ? (Al + (long)bz * sA) : nullptr;
    const short* pBl = (NTERMS == 3) ? (Bl + (long)bz * sB) : nullptr;

    // staging: thread t -> row t>>2, k-subchunk (t&3)*8; LDS byte off = 16*t
    const int srow = tid >> 2;
    const int skq  = (tid & 3) * 8;
    const int lds_off = srow * 32 + skq;
    const long ga0 = (tile_m + srow) * (long)lda + skq;
    const long gb0 = (tile_n + srow) * (long)ldb + skq;

    auto stage = [&](int k0, int buf) {
        short* s   = smem + buf * SET;
        short* ash = s;
        short* bsh = s + 128 * 32;
        gload_lds16(pAh + ga0 + k0,             ash + lds_off);
        gload_lds16(pAh + ga0 + 64l * lda + k0, ash + lds_off + 64 * 32);
        gload_lds16(pBh + gb0 + k0,             bsh + lds_off);
        gload_lds16(pBh + gb0 + 64l * ldb + k0, bsh + lds_off + 64 * 32);
        if constexpr (NTERMS == 3) {
            short* asl = s + 2 * 128 * 32;
            short* bsl = s + 3 * 128 * 32;
            gload_lds16(pAl + ga0 + k0,             asl + lds_off);
            gload_lds16(pAl + ga0 + 64l * lda + k0, asl + lds_off + 64 * 32);
            gload_lds16(pBl + gb0 + k0,             bsl + lds_off);
            gload_lds16(pBl + gb0 + 64l * ldb + k0, bsl + lds_off + 64 * 32);
        }
    };

    f32x4 acc[4][4] = {};
    stage(0, 0);
    int cur = 0;

    for (int k0 = 0; k0 < K; k0 += 32) {
        __syncthreads();                    // drains vmcnt: stage(cur) done
        if (k0 + 32 < K) stage(k0 + 32, cur ^ 1);   // prefetch next tile

        short* s   = smem + cur * SET;
        short* ash = s;
        short* bsh = s + 128 * 32;
        short* asl = s + 2 * 128 * 32;
        short* bsl = s + 3 * 128 * 32;

        short8 ah[4], bh[4], al[4], bl[4];
#pragma unroll
        for (int i = 0; i < 4; i++) {
            ah[i] = *(const short8*)&ash[(wm + i * 16 + l16) * 32 + quad * 8];
            bh[i] = *(const short8*)&bsh[(wn + i * 16 + l16) * 32 + quad * 8];
            if constexpr (NTERMS == 3) {
                al[i] = *(const short8*)&asl[(wm + i * 16 + l16) * 32 + quad * 8];
                bl[i] = *(const short8*)&bsl[(wn + i * 16 + l16) * 32 + quad * 8];
            }
        }
#pragma unroll
        for (int i = 0; i < 4; i++)
#pragma unroll
            for (int j = 0; j < 4; j++) {
                acc[i][j] = __builtin_amdgcn_mfma_f32_16x16x32_bf16(ah[i], bh[j], acc[i][j], 0, 0, 0);
                if constexpr (NTERMS == 3) {
                    acc[i][j] = __builtin_amdgcn_mfma_f32_16x16x32_bf16(ah[i], bl[j], acc[i][j], 0, 0, 0);
                    acc[i][j] = __builtin_amdgcn_mfma_f32_16x16x32_bf16(al[i], bh[j], acc[i][j], 0, 0, 0);
                }
            }
        cur ^= 1;
    }

    // epilogue: D row = quad*4 + reg, col = lane&15  (m89-verified mapping)
#pragma unroll
    for (int i = 0; i < 4; i++)
#pragma unroll
        for (int j = 0; j < 4; j++) {
            const long row0 = tile_m + wm + i * 16 + quad * 4;
            const long col  = tile_n + wn + j * 16 + l16;
#pragma unroll
            for (int r = 0; r < 4; r++) {
                float v = acc[i][j][r];
                if constexpr (SPLIT_OUT) {
                    long idx = (long)bz * sC + (row0 + r) * (long)ldc + col;
                    short h = f2bf(v);
                    Ch[idx] = h;
                    Cl[idx] = f2bf(v - bf2f(h));
                } else {
                    C[(long)bz * sC + (row0 + r) * (long)ldc + col] = v;
                }
            }
        }
}

// ---------------------------------------------------------------------------
// gemm3_256: C[m][n] = sum_k A[m][k]*B[n][k], 3-term split bf16.
// 256x256 tile, BK=32, 8 waves (2x4 of 128x64), 16x16x32 bf16 MFMA.
// LDS: 2 buffers x 4 planes (Ah,Al,Bh,Bl) x [256][32] shorts = 128 KiB.
//
// Swizzle (verified 0 bank conflicts): element (r,k) of a plane lives at
// 16B-chunk slot (k>>3) ^ ((r>>1)&3); applied by permuting the per-lane
// GLOBAL source chunk (global_load_lds dest stays linear) and XOR-ing the
// ds_read address.
//
// 6-phase schedule with TRUE vmcnt ladder (no vmcnt(0) in the loop).
// Staging for tile t+1: P0 Ah'(2), P1 Bh'(2), P2 Al'(2), P3 Bl'(2).
// Per-wave outstanding ledger (steady state; enter tile with {Al,Bl}=4):
//   P0: +Ah' -> 6
//   P1: +Bh' -> 8 ; vmcnt(6) drains Al(t)   [issued 1 tile ago]
//   P2: +Al' -> 8
//   P3: +Bl' -> 10; vmcnt(8) drains Bl(t)   [issued 1 tile ago]
//   P4: -
//   P5: vmcnt(4) drains Ah',Bh' [5 phases old] -> enter t+1 with {Al',Bl'}=4
// Phase bodies: {ds_read | stage | (vmcnt) | BAR | lgkm0+sched_barrier |
// setprio(1) 16 MFMA setprio(0)}.  Terms: P0 ahA.bh, P1 ahB.bh, P2 alA.bh,
// P3 alB.bh, P4 ahA.bl (bl read here), P5 ahB.bl (regs held from P0/P1).
// WAR: buf[cur^1] staging starts at P0, after prior tile's reads completed
// (phase-end barriers).  Last tile: waits 2 / 0 / skip.
// ---------------------------------------------------------------------------
__global__ __launch_bounds__(512, 2)
void gemm3_256(const short* __restrict__ Ah, const short* __restrict__ Al,
               const short* __restrict__ Bh, const short* __restrict__ Bl,
               float* __restrict__ C,
               int K, int lda, int ldb, int ldc,
               long sA, long sB, long sC, int nbx, int nby)
{
    extern __shared__ char smem_raw[];
    short* smem = (short*)smem_raw;
    constexpr int PL  = 256 * 32;          // 8192 shorts per plane (16 KiB)
    constexpr int SET = 4 * PL;            // shorts per buffer set

    const int t    = threadIdx.x;
    const int wave = t >> 6;
    const int lane = t & 63;
    const int quad = lane >> 4;
    const int l16  = lane & 15;
    const int wm   = (wave >> 2) * 128;    // 2 wave-rows
    const int wn   = (wave & 3) * 64;      // 4 wave-cols
    const int kslot8 = ((quad ^ ((l16 >> 1) & 3)) << 3);

    // bijective XCD swizzle (gridDim.x % 8 == 0): one batch per XCD
    const int nwg = gridDim.x;
    const int wg  = blockIdx.x;
    const int swz = (wg & 7) * (nwg >> 3) + (wg >> 3);
    const int per_b = nbx * nby;
    const int bz  = swz / per_b;
    const int rem = swz - bz * per_b;
    const long tile_m = (long)(rem / nbx) * 256;
    const long tile_n = (long)(rem % nbx) * 256;

    const short* pAh = Ah + (long)bz * sA;
    const short* pAl = Al + (long)bz * sA;
    const short* pBh = Bh + (long)bz * sB;
    const short* pBl = Bl + (long)bz * sB;

    // staging: thread t -> row t>>2 (half0) / +128 (half1), chunk slot t&3
    // holds global chunk (t&3) ^ ((row>>1)&3)  [read-side XOR matches]
    const int srow   = t >> 2;                       // 0..127
    const int schunk = (t & 3) ^ ((t >> 3) & 3);
    const long gA  = (tile_m + srow) * (long)lda + schunk * 8;
    const long gB  = (tile_n + srow) * (long)ldb + schunk * 8;
    const long gA2 = gA + 128l * lda;
    const long gB2 = gB + 128l * ldb;
    const int ld0 = t * 8;                           // shorts, linear dest

    f32x4 acc[8][4] = {};

    // prologue: full tile 0, issue order Ah,Bh,Al,Bl (ledger-consistent)
    {
        short* s = smem;
        gload_lds16(pAh + gA,  s + ld0);
        gload_lds16(pAh + gA2, s + ld0 + 4096);
        gload_lds16(pBh + gB,  s + 2 * PL + ld0);
        gload_lds16(pBh + gB2, s + 2 * PL + ld0 + 4096);
        gload_lds16(pAl + gA,  s + PL + ld0);
        gload_lds16(pAl + gA2, s + PL + ld0 + 4096);
        gload_lds16(pBl + gB,  s + 3 * PL + ld0);
        gload_lds16(pBl + gB2, s + 3 * PL + ld0 + 4096);
    }
    asm volatile("s_waitcnt vmcnt(4)" ::: "memory");   // Ah0,Bh0 landed
    __builtin_amdgcn_s_barrier();

    const int NT = K >> 5;
    int cur = 0;
#pragma unroll 1
    for (int kt = 0; kt < NT; ++kt) {
        const short* s    = smem + cur * SET;
        short* sn         = smem + (cur ^ 1) * SET;
        const short* ah_p = s;
        const short* al_p = s + PL;
        const short* bh_p = s + 2 * PL;
        const short* bl_p = s + 3 * PL;
        const int  k0n  = (kt + 1) << 5;
        const bool more = (kt + 1 < NT);

        short8 ahA[4], ahB[4], xbh[4], xbl[4], xal[4];

        // ---------------- P0: rd ahA,bh | stage Ah' | ahA.bh ----------------
#pragma unroll
        for (int i = 0; i < 4; i++)
            ahA[i] = *(const short8*)&ah_p[(wm + i * 16 + l16) * 32 + kslot8];
#pragma unroll
        for (int j = 0; j < 4; j++)
            xbh[j] = *(const short8*)&bh_p[(wn + j * 16 + l16) * 32 + kslot8];
        if (more) {
            gload_lds16(pAh + gA  + k0n, sn + ld0);
            gload_lds16(pAh + gA2 + k0n, sn + ld0 + 4096);
        }
        __builtin_amdgcn_s_barrier();
        asm volatile("s_waitcnt lgkmcnt(0)" ::: "memory");
        __builtin_amdgcn_sched_barrier(0);
        __builtin_amdgcn_s_setprio(1);
#pragma unroll
        for (int i = 0; i < 4; i++)
#pragma unroll
            for (int j = 0; j < 4; j++)
                acc[i][j] = __builtin_amdgcn_mfma_f32_16x16x32_bf16(ahA[i], xbh[j], acc[i][j], 0, 0, 0);
        __builtin_amdgcn_s_setprio(0);

        // ---------------- P1: rd ahB | stage Bh' | vmcnt(6) | ahB.bh ------
#pragma unroll
        for (int i = 0; i < 4; i++)
            ahB[i] = *(const short8*)&ah_p[(wm + 64 + i * 16 + l16) * 32 + kslot8];
        if (more) {
            gload_lds16(pBh + gB  + k0n, sn + 2 * PL + ld0);
            gload_lds16(pBh + gB2 + k0n, sn + 2 * PL + ld0 + 4096);
            asm volatile("s_waitcnt vmcnt(6)" ::: "memory");   // Al(t) landed
        } else {
            asm volatile("s_waitcnt vmcnt(2)" ::: "memory");
        }
        __builtin_amdgcn_s_barrier();
        asm volatile("s_waitcnt lgkmcnt(0)" ::: "memory");
        __builtin_amdgcn_sched_barrier(0);
        __builtin_amdgcn_s_setprio(1);
#pragma unroll
        for (int i = 0; i < 4; i++)
#pragma unroll
            for (int j = 0; j < 4; j++)
                acc[4 + i][j] = __builtin_amdgcn_mfma_f32_16x16x32_bf16(ahB[i], xbh[j], acc[4 + i][j], 0, 0, 0);
        __builtin_amdgcn_s_setprio(0);

        // ---------------- P2: rd alA | stage Al' | alA.bh ----------------
#pragma unroll
        for (int i = 0; i < 4; i++)
            xal[i] = *(const short8*)&al_p[(wm + i * 16 + l16) * 32 + kslot8];
        if (more) {
            gload_lds16(pAl + gA  + k0n, sn + PL + ld0);
            gload_lds16(pAl + gA2 + k0n, sn + PL + ld0 + 4096);
        }
        __builtin_amdgcn_s_barrier();
        asm volatile("s_waitcnt lgkmcnt(0)" ::: "memory");
        __builtin_amdgcn_sched_barrier(0);
        __builtin_amdgcn_s_setprio(1);
#pragma unroll
        for (int i = 0; i < 4; i++)
#pragma unroll
            for (int j = 0; j < 4; j++)
                acc[i][j] = __builtin_amdgcn_mfma_f32_16x16x32_bf16(xal[i], xbh[j], acc[i][j], 0, 0, 0);
        __builtin_amdgcn_s_setprio(0);

        // ---------------- P3: rd alB | stage Bl' | vmcnt(8) | alB.bh ------
#pragma unroll
        for (int i = 0; i < 4; i++)
            xal[i] = *(const short8*)&al_p[(wm + 64 + i * 16 + l16) * 32 + kslot8];
        if (more) {
            gload_lds16(pBl + gB  + k0n, sn + 3 * PL + ld0);
            gload_lds16(pBl + gB2 + k0n, sn + 3 * PL + ld0 + 4096);
            asm volatile("s_waitcnt vmcnt(8)" ::: "memory");   // Bl(t) landed
        } else {
            asm volatile("s_waitcnt vmcnt(0)" ::: "memory");
        }
        __builtin_amdgcn_s_barrier();
        asm volatile("s_waitcnt lgkmcnt(0)" ::: "memory");
        __builtin_amdgcn_sched_barrier(0);
        __builtin_amdgcn_s_setprio(1);
#pragma unroll
        for (int i = 0; i < 4; i++)
#pragma unroll
            for (int j = 0; j < 4; j++)
                acc[4 + i][j] = __builtin_amdgcn_mfma_f32_16x16x32_bf16(xal[i], xbh[j], acc[4 + i][j], 0, 0, 0);
        __builtin_amdgcn_s_setprio(0);

        // ---------------- P4: rd bl | ahA.bl ----------------
#pragma unroll
        for (int j = 0; j < 4; j++)
            xbl[j] = *(const short8*)&bl_p[(wn + j * 16 + l16) * 32 + kslot8];
        __builtin_amdgcn_s_barrier();
        asm volatile("s_waitcnt lgkmcnt(0)" ::: "memory");
        __builtin_amdgcn_sched_barrier(0);
        __builtin_amdgcn_s_setprio(1);
#pragma unroll
        for (int i = 0; i < 4; i++)
#pragma unroll
            for (int j = 0; j < 4; j++)
                acc[i][j] = __builtin_amdgcn_mfma_f32_16x16x32_bf16(ahA[i], xbl[j], acc[i][j], 0, 0, 0);
        __builtin_amdgcn_s_setprio(0);

        // ---------------- P5: ahB.bl | vmcnt(4) ladder ----------------
        __builtin_amdgcn_s_setprio(1);
#pragma unroll
        for (int i = 0; i < 4; i++)
#pragma unroll
            for (int j = 0; j < 4; j++)
                acc[4 + i][j] = __builtin_amdgcn_mfma_f32_16x16x32_bf16(ahB[i], xbl[j], acc[4 + i][j], 0, 0, 0);
        __builtin_amdgcn_s_setprio(0);
        if (more) {
            asm volatile("s_waitcnt vmcnt(4)" ::: "memory");   // Ah',Bh' landed
            __builtin_amdgcn_s_barrier();
        }

        cur ^= 1;
    }

    // epilogue: D row = quad*4 + reg, col = lane&15  (m89-verified mapping)
#pragma unroll
    for (int i = 0; i < 8; i++)
#pragma unroll
        for (int j = 0; j < 4; j++) {
            const long row0 = tile_m + wm + i * 16 + quad * 4;
            const long col  = tile_n + wn + j * 16 + l16;
#pragma unroll
            for (int r = 0; r < 4; r++)
                C[(long)bz * sC + (row0 + r) * (long)ldc + col] = acc[i][j][r];
        }
}

// ---------------------------------------------------------------------------
// Row softmax over 2048 fp32 logits; writes P as contiguous bf16.
// ---------------------------------------------------------------------------
__global__ __launch_bounds__(256)
void softmax_kernel(const float* __restrict__ logits, short* __restrict__ P)
{
    const long row = blockIdx.x;
    const float* p = logits + row * 2048;
    const int tid = threadIdx.x;
    const int lane = tid & 63, wave = tid >> 6;

    f32x4 v0 = *(const f32x4*)(p + tid * 8);
    f32x4 v1 = *(const f32x4*)(p + tid * 8 + 4);

    float m = fmaxf(fmaxf(fmaxf(v0[0], v0[1]), fmaxf(v0[2], v0[3])),
                    fmaxf(fmaxf(v1[0], v1[1]), fmaxf(v1[2], v1[3])));
#pragma unroll
    for (int o = 32; o > 0; o >>= 1) m = fmaxf(m, __shfl_xor(m, o));

    __shared__ float red[8];
    if (lane == 0) red[wave] = m;
    __syncthreads();
    m = fmaxf(fmaxf(red[0], red[1]), fmaxf(red[2], red[3]));

    float e[8];
    float s = 0.f;
#pragma unroll
    for (int i = 0; i < 4; i++) { e[i] = __expf(v0[i] - m); s += e[i]; }
#pragma unroll
    for (int i = 0; i < 4; i++) { e[4 + i] = __expf(v1[i] - m); s += e[4 + i]; }
#pragma unroll
    for (int o = 32; o > 0; o >>= 1) s += __shfl_xor(s, o);
    if (lane == 0) red[4 + wave] = s;
    __syncthreads();
    const float inv = 1.f / (red[4] + red[5] + red[6] + red[7]);

    short8 ob;
#pragma unroll
    for (int i = 0; i < 8; i++) ob[i] = f2bf(e[i] * inv);
    *(short8*)(P + row * 2048 + tid * 8) = ob;
}

// ---------------------------------------------------------------------------
extern "C" void kernel_launch(void* const* d_in, const int* in_sizes, int n_in,
                              void* d_out, int out_size, void* d_ws, size_t ws_size,
                              hipStream_t stream)
{
    const float* enc = (const float*)d_in[0];   // [8,2048,512]
    const float* dec = (const float*)d_in[1];   // [8,2048,512]
    const float* W   = (const float*)d_in[2];   // [512,512]
    float* out = (float*)d_out;                 // [8,2048,512]

    const long BSE = 8l * 2048 * 512;           // 8388608
    const long NW  = 512l * 512;

    char* p = (char*)d_ws;
    auto take = [&](long bytes) { char* r = p; p += (bytes + 255) & ~255l; return r; };
    short* enc_hi = (short*)take(BSE * 2);
    short* enc_lo = (short*)take(BSE * 2);
    short* dec_hi = (short*)take(BSE * 2);
    short* dec_lo = (short*)take(BSE * 2);
    short* ep_hi  = (short*)take(BSE * 2);
    short* ep_lo  = (short*)take(BSE * 2);
    short* enc_t  = (short*)take(BSE * 2);
    short* wt_hi  = (short*)take(NW * 2);
    short* wt_lo  = (short*)take(NW * 2);
    float* logits = (float*)take(8l * 2048 * 2048 * 4);   // total ~253 MB
    // P [8][2048][2048] bf16 = 67.1 MB: aliases enc_hi..dec_lo (4 x 16.78 MB,
    // contiguous, all dead once softmax runs).
    short* Pbuf = enc_hi;
    (void)ws_size; (void)in_sizes; (void)n_in; (void)out_size;

    // one-time: allow 128 KiB dynamic LDS for gemm3_256 (host-side, not a
    // stream op -> graph-capture safe)
    static bool attr_set = false;
    if (!attr_set) {
        (void)hipFuncSetAttribute((const void*)gemm3_256,
                                  hipFuncAttributeMaxDynamicSharedMemorySize,
                                  131072);
        attr_set = true;
    }

    // enc: split + transpose fused (reads enc once)
    split_transpose_kernel<<<dim3(64, 16, 8), 256, 0, stream>>>(
        enc, enc_hi, enc_lo, enc_t);
    split_kernel<<<4096, 256, 0, stream>>>(dec, dec_hi, dec_lo);
    split_w_kernel<<<1024, 256, 0, stream>>>(W, wt_hi, wt_lo);

    // enc_proj = enc @ W  (M=16384, N=512, K=512), 3-term, split bf16 output
    gemm_bt<3, true><<<dim3(4, 128, 1), 256, 64 * 1024, stream>>>(
        enc_hi, enc_lo, wt_hi, wt_lo, nullptr, ep_hi, ep_lo,
        512, 512, 512, 512, 0, 0, 0);

    // logits[b] = dec[b] @ ep[b]^T  (M=2048, N=2048, K=512) x 8, 3-term
    // 256x256 tiles: 8x8 tiles x 8 batches = 512 blocks (XCD-swizzled inside)
    gemm3_256<<<512, 512, 131072, stream>>>(
        dec_hi, dec_lo, ep_hi, ep_lo, logits,
        512, 512, 512, 2048, 2048l * 512, 2048l * 512, 2048l * 2048, 8, 8);

    softmax_kernel<<<16384, 256, 0, stream>>>(logits, Pbuf);

    // out[b] = P[b] @ enc[b]  (M=2048, N=512, K=2048) x 8, plain bf16
    gemm_bt<1, false><<<dim3(4, 16, 8), 256, 32 * 1024, stream>>>(
        Pbuf, nullptr, enc_t, nullptr, out, nullptr, nullptr,
        2048, 2048, 2048, 512, 2048l * 2048, 512l * 2048, 2048l * 512);
}

// Round 8
// 319.503 us; speedup vs baseline: 1.0637x; 1.0637x over previous
//
#include <hip/hip_runtime.h>
#include <cstdint>

// ---------------------------------------------------------------------------
// Attention (Luong general): out = softmax(dec @ (enc@W)^T) @ enc
// B=8, S_enc=S_dec=2048, H=512, fp32 in/out.
//
// bf16 MFMA; split-precision (hi+lo bf16, 3-term) for the two matmuls feeding
// softmax; plain bf16 for PV.
// Round 10: seven schedule variants all pinned at 39-44% MfmaUtil (the
// short-K grouped-GEMM regime: 8-phase transfer = +10%, m248). Pivot to the
// pipeline: fuse softmax INTO gemm3's epilogue (flash-style, 2-pass):
//   - gemm3 epilogue: per-(row, 256-tile) max+sumexp via shfl + 5KB LDS
//     cross-wave reduce; writes P~ = exp(v - m_t) bf16 (67 MB, half the old
//     fp32 logits write) + stats (1 MB). K-loop untouched (round-7 ladder).
//   - combine kernel: scale[row][t] = exp(m_t - M)/S  (16K rows, ~1 us).
//   - PV (gemm_pv): unchanged hot loop; folds oacc += scale*acc every 8
//     K-tiles (8 folds). Numerically identical to the old P path (one bf16
//     rounding, exact fp32 scale).
// Eliminates the softmax kernel's 201 MB round-trip entirely.
// ---------------------------------------------------------------------------

#define DEVINL __device__ __forceinline__

typedef __attribute__((ext_vector_type(8))) short short8;
typedef __attribute__((ext_vector_type(4))) float f32x4;

DEVINL short f2bf(float x) {
    union { float f; uint32_t u; } v; v.f = x;
    uint32_t r = v.u + 0x7FFFu + ((v.u >> 16) & 1u);   // RNE
    return (short)(r >> 16);
}
DEVINL float bf2f(short h) {
    union { uint32_t u; float f; } v; v.u = ((uint32_t)(uint16_t)h) << 16;
    return v.f;
}

DEVINL void gload_lds16(const void* g, void* l) {
    __builtin_amdgcn_global_load_lds(
        (const __attribute__((address_space(1))) char*)g,
        (__attribute__((address_space(3))) char*)l, 16, 0, 0);
}

// ---------------------------------------------------------------------------
// split fp32 -> (hi, lo) bf16 arrays.  8 elems/thread, exact-cover grids.
// ---------------------------------------------------------------------------
__global__ __launch_bounds__(256)
void split_kernel(const float* __restrict__ x, short* __restrict__ hi,
                  short* __restrict__ lo)
{
    long i = ((long)blockIdx.x * 256 + threadIdx.x) * 8;
    f32x4 a = *(const f32x4*)(x + i);
    f32x4 b = *(const f32x4*)(x + i + 4);
    short8 h, l;
#pragma unroll
    for (int j = 0; j < 4; j++) {
        short ha = f2bf(a[j]); h[j] = ha;     l[j] = f2bf(a[j] - bf2f(ha));
        short hb = f2bf(b[j]); h[4 + j] = hb; l[4 + j] = f2bf(b[j] - bf2f(hb));
    }
    *(short8*)(hi + i) = h;
    *(short8*)(lo + i) = l;
}

// W[512k][512n] -> Wt_hi/lo[n][k]
__global__ __launch_bounds__(256)
void split_w_kernel(const float* __restrict__ w, short* __restrict__ wth,
                    short* __restrict__ wtl)
{
    int idx = blockIdx.x * 256 + threadIdx.x;   // k*512 + n
    int k = idx >> 9, n = idx & 511;
    float v = w[idx];
    short h = f2bf(v);
    wth[(long)n * 512 + k] = h;
    wtl[(long)n * 512 + k] = f2bf(v - bf2f(h));
}

// Fused: enc[b][s][e] fp32 -> enc_hi/enc_lo [b][s][e] bf16 + enc_t[b][e][s]
// bf16 (PV B-operand).  Reads enc exactly once.
__global__ __launch_bounds__(256)
void split_transpose_kernel(const float* __restrict__ x, short* __restrict__ hi,
                            short* __restrict__ lo, short* __restrict__ xt)
{
    __shared__ short tile[32][33];
    const int b  = blockIdx.z;
    const int s0 = blockIdx.x * 32;
    const int e0 = blockIdx.y * 32;
    const float* px = x + (long)b * 2048 * 512;
    short* ph = hi + (long)b * 2048 * 512;
    short* pl = lo + (long)b * 2048 * 512;
    short* pt = xt + (long)b * 512 * 2048;
    const int tx = threadIdx.x & 31;
    const int ty = threadIdx.x >> 5;   // 0..7
#pragma unroll
    for (int r = 0; r < 32; r += 8) {
        long idx = (long)(s0 + ty + r) * 512 + e0 + tx;
        float v = px[idx];
        short h = f2bf(v);
        ph[idx] = h;
        pl[idx] = f2bf(v - bf2f(h));
        tile[ty + r][tx] = h;
    }
    __syncthreads();
#pragma unroll
    for (int r = 0; r < 32; r += 8)
        pt[(long)(e0 + ty + r) * 2048 + s0 + tx] = tile[tx][ty + r];
}

// ---------------------------------------------------------------------------
// gemm_bt: C[m][n] = sum_k A[m][k]*B[n][k]  (both operands K-contiguous).
// 128x128 tile, BK=32, 4 waves (2x2 of 64x64), 16x16x32 bf16 MFMA.
// (kept for the enc@W projection; 3-term split output path)
// ---------------------------------------------------------------------------
template<int NTERMS, bool SPLIT_OUT>
__global__ __launch_bounds__(256, 2)
void gemm_bt(const short* __restrict__ Ah, const short* __restrict__ Al,
             const short* __restrict__ Bh, const short* __restrict__ Bl,
             float* __restrict__ C, short* __restrict__ Ch, short* __restrict__ Cl,
             int K, int lda, int ldb, int ldc,
             long sA, long sB, long sC)
{
    extern __shared__ char smem_raw[];
    constexpr int OPS = (NTERMS == 3) ? 4 : 2;     // operand planes per set
    constexpr int SET = 128 * 32 * OPS;            // shorts per buffer set
    short* smem = (short*)smem_raw;                // 2 sets

    const int tid  = threadIdx.x;
    const int wave = tid >> 6;
    const int lane = tid & 63;
    const int quad = lane >> 4;
    const int l16  = lane & 15;
    const int wm   = (wave >> 1) * 64;
    const int wn   = (wave & 1) * 64;

    const long tile_m = (long)blockIdx.y * 128;
    const long tile_n = (long)blockIdx.x * 128;
    const int  bz     = blockIdx.z;

    const short* pAh = Ah + (long)bz * sA;
    const short* pBh = Bh + (long)bz * sB;
    const short* pAl = (NTERMS == 3) ? (Al + (long)bz * sA) : nullptr;
    const short* pBl = (NTERMS == 3) ? (Bl + (long)bz * sB) : nullptr;

    // staging: thread t -> row t>>2, k-subchunk (t&3)*8; LDS byte off = 16*t
    const int srow = tid >> 2;
    const int skq  = (tid & 3) * 8;
    const int lds_off = srow * 32 + skq;
    const long ga0 = (tile_m + srow) * (long)lda + skq;
    const long gb0 = (tile_n + srow) * (long)ldb + skq;

    auto stage = [&](int k0, int buf) {
        short* s   = smem + buf * SET;
        short* ash = s;
        short* bsh = s + 128 * 32;
        gload_lds16(pAh + ga0 + k0,             ash + lds_off);
        gload_lds16(pAh + ga0 + 64l * lda + k0, ash + lds_off + 64 * 32);
        gload_lds16(pBh + gb0 + k0,             bsh + lds_off);
        gload_lds16(pBh + gb0 + 64l * ldb + k0, bsh + lds_off + 64 * 32);
        if constexpr (NTERMS == 3) {
            short* asl = s + 2 * 128 * 32;
            short* bsl = s + 3 * 128 * 32;
            gload_lds16(pAl + ga0 + k0,             asl + lds_off);
            gload_lds16(pAl + ga0 + 64l * lda + k0, asl + lds_off + 64 * 32);
            gload_lds16(pBl + gb0 + k0,             bsl + lds_off);
            gload_lds16(pBl + gb0 + 64l * ldb + k0, bsl + lds_off + 64 * 32);
        }
    };

    f32x4 acc[4][4] = {};
    stage(0, 0);
    int cur = 0;

    for (int k0 = 0; k0 < K; k0 += 32) {
        __syncthreads();                    // drains vmcnt: stage(cur) done
        if (k0 + 32 < K) stage(k0 + 32, cur ^ 1);   // prefetch next tile

        short* s   = smem + cur * SET;
        short* ash = s;
        short* bsh = s + 128 * 32;
        short* asl = s + 2 * 128 * 32;
        short* bsl = s + 3 * 128 * 32;

        short8 ah[4], bh[4], al[4], bl[4];
#pragma unroll
        for (int i = 0; i < 4; i++) {
            ah[i] = *(const short8*)&ash[(wm + i * 16 + l16) * 32 + quad * 8];
            bh[i] = *(const short8*)&bsh[(wn + i * 16 + l16) * 32 + quad * 8];
            if constexpr (NTERMS == 3) {
                al[i] = *(const short8*)&asl[(wm + i * 16 + l16) * 32 + quad * 8];
                bl[i] = *(const short8*)&bsl[(wn + i * 16 + l16) * 32 + quad * 8];
            }
        }
#pragma unroll
        for (int i = 0; i < 4; i++)
#pragma unroll
            for (int j = 0; j < 4; j++) {
                acc[i][j] = __builtin_amdgcn_mfma_f32_16x16x32_bf16(ah[i], bh[j], acc[i][j], 0, 0, 0);
                if constexpr (NTERMS == 3) {
                    acc[i][j] = __builtin_amdgcn_mfma_f32_16x16x32_bf16(ah[i], bl[j], acc[i][j], 0, 0, 0);
                    acc[i][j] = __builtin_amdgcn_mfma_f32_16x16x32_bf16(al[i], bh[j], acc[i][j], 0, 0, 0);
                }
            }
        cur ^= 1;
    }

    // epilogue: D row = quad*4 + reg, col = lane&15  (m89-verified mapping)
#pragma unroll
    for (int i = 0; i < 4; i++)
#pragma unroll
        for (int j = 0; j < 4; j++) {
            const long row0 = tile_m + wm + i * 16 + quad * 4;
            const long col  = tile_n + wn + j * 16 + l16;
#pragma unroll
            for (int r = 0; r < 4; r++) {
                float v = acc[i][j][r];
                if constexpr (SPLIT_OUT) {
                    long idx = (long)bz * sC + (row0 + r) * (long)ldc + col;
                    short h = f2bf(v);
                    Ch[idx] = h;
                    Cl[idx] = f2bf(v - bf2f(h));
                } else {
                    C[(long)bz * sC + (row0 + r) * (long)ldc + col] = v;
                }
            }
        }
}

// ---------------------------------------------------------------------------
// gemm3_256: logits tile + FUSED tile-softmax epilogue.
// 256x256 tile, BK=32, 8 waves (2x4 of 128x64), 16x16x32 bf16 MFMA.
// LDS: 2 buffers x 4 planes (Ah,Al,Bh,Bl) x [256][32] shorts = 128 KiB.
// K-loop: round-7 verified structure (swizzle 0-conflict, 6 phases, counted
// vmcnt ladder 6/8/4, setprio, no mid-loop drain-to-0).
//
// Epilogue (new): per-(row, this 256-col tile) softmax pieces:
//   A: per-wave row-max over its 64 cols (shfl width16) -> lmax[4][256] LDS
//   B: rowm[256] = max over the 4 col-waves
//   C: P~ = exp(v - rowm) -> bf16 store; partial sums -> lsum[4][256]
//   D: stats[bz][row][nt] = {rowm, sum}
// ---------------------------------------------------------------------------
__global__ __launch_bounds__(512, 2)
void gemm3_256(const short* __restrict__ Ah, const short* __restrict__ Al,
               const short* __restrict__ Bh, const short* __restrict__ Bl,
               short* __restrict__ Pt, float* __restrict__ stats,
               int K, int lda, int ldb,
               long sA, long sB, int nbx, int nby)
{
    extern __shared__ char smem_raw[];
    short* smem = (short*)smem_raw;
    constexpr int PL  = 256 * 32;          // 8192 shorts per plane (16 KiB)
    constexpr int SET = 4 * PL;            // shorts per buffer set

    const int t    = threadIdx.x;
    const int wave = t >> 6;
    const int lane = t & 63;
    const int quad = lane >> 4;
    const int l16  = lane & 15;
    const int wm   = (wave >> 2) * 128;    // 2 wave-rows
    const int wn   = (wave & 3) * 64;      // 4 wave-cols
    const int kslot8 = ((quad ^ ((l16 >> 1) & 3)) << 3);

    // bijective XCD swizzle (gridDim.x % 8 == 0): one batch per XCD
    const int nwg = gridDim.x;
    const int wg  = blockIdx.x;
    const int swz = (wg & 7) * (nwg >> 3) + (wg >> 3);
    const int per_b = nbx * nby;
    const int bz  = swz / per_b;
    const int rem = swz - bz * per_b;
    const long tile_m = (long)(rem / nbx) * 256;
    const long tile_n = (long)(rem % nbx) * 256;

    const short* pAh = Ah + (long)bz * sA;
    const short* pAl = Al + (long)bz * sA;
    const short* pBh = Bh + (long)bz * sB;
    const short* pBl = Bl + (long)bz * sB;

    // staging: thread t -> row t>>2 (half0) / +128 (half1), chunk slot t&3
    // holds global chunk (t&3) ^ ((row>>1)&3)  [read-side XOR matches]
    const int srow   = t >> 2;                       // 0..127
    const int schunk = (t & 3) ^ ((t >> 3) & 3);
    const long gA  = (tile_m + srow) * (long)lda + schunk * 8;
    const long gB  = (tile_n + srow) * (long)ldb + schunk * 8;
    const long gA2 = gA + 128l * lda;
    const long gB2 = gB + 128l * ldb;
    const int ld0 = t * 8;                           // shorts, linear dest

    f32x4 acc[8][4] = {};

    // prologue: full tile 0, issue order Ah,Bh,Al,Bl (ledger-consistent)
    {
        short* s = smem;
        gload_lds16(pAh + gA,  s + ld0);
        gload_lds16(pAh + gA2, s + ld0 + 4096);
        gload_lds16(pBh + gB,  s + 2 * PL + ld0);
        gload_lds16(pBh + gB2, s + 2 * PL + ld0 + 4096);
        gload_lds16(pAl + gA,  s + PL + ld0);
        gload_lds16(pAl + gA2, s + PL + ld0 + 4096);
        gload_lds16(pBl + gB,  s + 3 * PL + ld0);
        gload_lds16(pBl + gB2, s + 3 * PL + ld0 + 4096);
    }
    asm volatile("s_waitcnt vmcnt(4)" ::: "memory");   // Ah0,Bh0 landed
    __builtin_amdgcn_s_barrier();

    const int NT = K >> 5;
    int cur = 0;
#pragma unroll 1
    for (int kt = 0; kt < NT; ++kt) {
        const short* s    = smem + cur * SET;
        short* sn         = smem + (cur ^ 1) * SET;
        const short* ah_p = s;
        const short* al_p = s + PL;
        const short* bh_p = s + 2 * PL;
        const short* bl_p = s + 3 * PL;
        const int  k0n  = (kt + 1) << 5;
        const bool more = (kt + 1 < NT);

        short8 ahA[4], ahB[4], xbh[4], xbl[4], xal[4];

        // ---------------- P0: rd ahA,bh | stage Ah' | ahA.bh ----------------
#pragma unroll
        for (int i = 0; i < 4; i++)
            ahA[i] = *(const short8*)&ah_p[(wm + i * 16 + l16) * 32 + kslot8];
#pragma unroll
        for (int j = 0; j < 4; j++)
            xbh[j] = *(const short8*)&bh_p[(wn + j * 16 + l16) * 32 + kslot8];
        if (more) {
            gload_lds16(pAh + gA  + k0n, sn + ld0);
            gload_lds16(pAh + gA2 + k0n, sn + ld0 + 4096);
        }
        __builtin_amdgcn_s_barrier();
        asm volatile("s_waitcnt lgkmcnt(0)" ::: "memory");
        __builtin_amdgcn_sched_barrier(0);
        __builtin_amdgcn_s_setprio(1);
#pragma unroll
        for (int i = 0; i < 4; i++)
#pragma unroll
            for (int j = 0; j < 4; j++)
                acc[i][j] = __builtin_amdgcn_mfma_f32_16x16x32_bf16(ahA[i], xbh[j], acc[i][j], 0, 0, 0);
        __builtin_amdgcn_s_setprio(0);

        // ---------------- P1: rd ahB | stage Bh' | vmcnt(6) | ahB.bh ------
#pragma unroll
        for (int i = 0; i < 4; i++)
            ahB[i] = *(const short8*)&ah_p[(wm + 64 + i * 16 + l16) * 32 + kslot8];
        if (more) {
            gload_lds16(pBh + gB  + k0n, sn + 2 * PL + ld0);
            gload_lds16(pBh + gB2 + k0n, sn + 2 * PL + ld0 + 4096);
            asm volatile("s_waitcnt vmcnt(6)" ::: "memory");   // Al(t) landed
        } else {
            asm volatile("s_waitcnt vmcnt(2)" ::: "memory");
        }
        __builtin_amdgcn_s_barrier();
        asm volatile("s_waitcnt lgkmcnt(0)" ::: "memory");
        __builtin_amdgcn_sched_barrier(0);
        __builtin_amdgcn_s_setprio(1);
#pragma unroll
        for (int i = 0; i < 4; i++)
#pragma unroll
            for (int j = 0; j < 4; j++)
                acc[4 + i][j] = __builtin_amdgcn_mfma_f32_16x16x32_bf16(ahB[i], xbh[j], acc[4 + i][j], 0, 0, 0);
        __builtin_amdgcn_s_setprio(0);

        // ---------------- P2: rd alA | stage Al' | alA.bh ----------------
#pragma unroll
        for (int i = 0; i < 4; i++)
            xal[i] = *(const short8*)&al_p[(wm + i * 16 + l16) * 32 + kslot8];
        if (more) {
            gload_lds16(pAl + gA  + k0n, sn + PL + ld0);
            gload_lds16(pAl + gA2 + k0n, sn + PL + ld0 + 4096);
        }
        __builtin_amdgcn_s_barrier();
        asm volatile("s_waitcnt lgkmcnt(0)" ::: "memory");
        __builtin_amdgcn_sched_barrier(0);
        __builtin_amdgcn_s_setprio(1);
#pragma unroll
        for (int i = 0; i < 4; i++)
#pragma unroll
            for (int j = 0; j < 4; j++)
                acc[i][j] = __builtin_amdgcn_mfma_f32_16x16x32_bf16(xal[i], xbh[j], acc[i][j], 0, 0, 0);
        __builtin_amdgcn_s_setprio(0);

        // ---------------- P3: rd alB | stage Bl' | vmcnt(8) | alB.bh ------
#pragma unroll
        for (int i = 0; i < 4; i++)
            xal[i] = *(const short8*)&al_p[(wm + 64 + i * 16 + l16) * 32 + kslot8];
        if (more) {
            gload_lds16(pBl + gB  + k0n, sn + 3 * PL + ld0);
            gload_lds16(pBl + gB2 + k0n, sn + 3 * PL + ld0 + 4096);
            asm volatile("s_waitcnt vmcnt(8)" ::: "memory");   // Bl(t) landed
        } else {
            asm volatile("s_waitcnt vmcnt(0)" ::: "memory");
        }
        __builtin_amdgcn_s_barrier();
        asm volatile("s_waitcnt lgkmcnt(0)" ::: "memory");
        __builtin_amdgcn_sched_barrier(0);
        __builtin_amdgcn_s_setprio(1);
#pragma unroll
        for (int i = 0; i < 4; i++)
#pragma unroll
            for (int j = 0; j < 4; j++)
                acc[4 + i][j] = __builtin_amdgcn_mfma_f32_16x16x32_bf16(xal[i], xbh[j], acc[4 + i][j], 0, 0, 0);
        __builtin_amdgcn_s_setprio(0);

        // ---------------- P4: rd bl | ahA.bl ----------------
#pragma unroll
        for (int j = 0; j < 4; j++)
            xbl[j] = *(const short8*)&bl_p[(wn + j * 16 + l16) * 32 + kslot8];
        __builtin_amdgcn_s_barrier();
        asm volatile("s_waitcnt lgkmcnt(0)" ::: "memory");
        __builtin_amdgcn_sched_barrier(0);
        __builtin_amdgcn_s_setprio(1);
#pragma unroll
        for (int i = 0; i < 4; i++)
#pragma unroll
            for (int j = 0; j < 4; j++)
                acc[i][j] = __builtin_amdgcn_mfma_f32_16x16x32_bf16(ahA[i], xbl[j], acc[i][j], 0, 0, 0);
        __builtin_amdgcn_s_setprio(0);

        // ---------------- P5: ahB.bl | vmcnt(4) ladder ----------------
        __builtin_amdgcn_s_setprio(1);
#pragma unroll
        for (int i = 0; i < 4; i++)
#pragma unroll
            for (int j = 0; j < 4; j++)
                acc[4 + i][j] = __builtin_amdgcn_mfma_f32_16x16x32_bf16(ahB[i], xbl[j], acc[4 + i][j], 0, 0, 0);
        __builtin_amdgcn_s_setprio(0);
        if (more) {
            asm volatile("s_waitcnt vmcnt(4)" ::: "memory");   // Ah',Bh' landed
            __builtin_amdgcn_s_barrier();
        }

        cur ^= 1;
    }

    // ---- fused softmax epilogue (rows: wr*128 + i*16 + quad*4 + r) ----
    float* sf   = (float*)smem_raw;
    float* lmax = sf;                   // [4][256]
    float* rowm = sf + 1024;            // [256]
    const int wr = wave >> 2, wc = wave & 3;
    __syncthreads();                    // K-loop fully done, LDS reusable

    // A: per-wave per-row max over its 64 cols
#pragma unroll
    for (int i = 0; i < 8; i++)
#pragma unroll
        for (int r = 0; r < 4; r++) {
            float m = acc[i][0][r];
#pragma unroll
            for (int j = 1; j < 4; j++) m = fmaxf(m, acc[i][j][r]);
#pragma unroll
            for (int o = 1; o < 16; o <<= 1) m = fmaxf(m, __shfl_xor(m, o));
            if (l16 == 0) lmax[wc * 256 + wr * 128 + i * 16 + quad * 4 + r] = m;
        }
    __syncthreads();
    // B: combine across the 4 col-waves
    if (t < 256)
        rowm[t] = fmaxf(fmaxf(lmax[t], lmax[256 + t]),
                        fmaxf(lmax[512 + t], lmax[768 + t]));
    __syncthreads();
    // C: P~ = exp(v - rowm) -> bf16; partial sums -> lsum (aliases lmax)
    float* lsum = sf;
    short* PtB  = Pt + (long)bz * 2048 * 2048;
#pragma unroll
    for (int i = 0; i < 8; i++)
#pragma unroll
        for (int r = 0; r < 4; r++) {
            const int rit = wr * 128 + i * 16 + quad * 4 + r;
            const float m = rowm[rit];
            float sum = 0.f;
#pragma unroll
            for (int j = 0; j < 4; j++) {
                float e = __expf(acc[i][j][r] - m);
                sum += e;
                PtB[(tile_m + rit) * 2048 + tile_n + wn + j * 16 + l16] = f2bf(e);
            }
#pragma unroll
            for (int o = 1; o < 16; o <<= 1) sum += __shfl_xor(sum, o);
            if (l16 == 0) lsum[wc * 256 + rit] = sum;
        }
    __syncthreads();
    // D: stats {m, s} per (row, this 256-tile)
    if (t < 256) {
        float S = lsum[t] + lsum[256 + t] + lsum[512 + t] + lsum[768 + t];
        const long sidx = (((long)bz * 2048 + tile_m + t) * 8 + (tile_n >> 8)) * 2;
        stats[sidx]     = rowm[t];
        stats[sidx + 1] = S;
    }
}

// ---------------------------------------------------------------------------
// combine: per dec-row global max + sum -> scale[row][t] = exp(m_t - M)/S
// ---------------------------------------------------------------------------
__global__ __launch_bounds__(256)
void combine_kernel(const float* __restrict__ stats, float* __restrict__ scales)
{
    const long row = (long)blockIdx.x * 256 + threadIdx.x;   // 0..16383
    const float* p = stats + row * 16;
    float m[8], s[8];
#pragma unroll
    for (int t = 0; t < 8; t++) { m[t] = p[t * 2]; s[t] = p[t * 2 + 1]; }
    float M = m[0];
#pragma unroll
    for (int t = 1; t < 8; t++) M = fmaxf(M, m[t]);
    float S = 0.f;
#pragma unroll
    for (int t = 0; t < 8; t++) S += s[t] * __expf(m[t] - M);
    const float inv = 1.f / S;
#pragma unroll
    for (int t = 0; t < 8; t++)
        scales[row * 8 + t] = __expf(m[t] - M) * inv;
}

// ---------------------------------------------------------------------------
// gemm_pv: out[m][e] = sum_t scale[m][t] * sum_{k in t} P~[m][k]*encT[e][k]
// 128x128 tile, BK=32, 4 waves; hot loop identical to gemm_bt<1>; folds
// oacc += scale*acc at every 256-k boundary (8 folds).
// ---------------------------------------------------------------------------
__global__ __launch_bounds__(256, 2)
void gemm_pv(const short* __restrict__ A, const short* __restrict__ B,
             const float* __restrict__ scales, float* __restrict__ C,
             int K, int lda, int ldb, int ldc,
             long sA, long sB, long sC)
{
    extern __shared__ char smem_raw[];
    constexpr int SET = 128 * 32 * 2;              // shorts per buffer set
    short* smem = (short*)smem_raw;                // 2 sets

    const int tid  = threadIdx.x;
    const int wave = tid >> 6;
    const int lane = tid & 63;
    const int quad = lane >> 4;
    const int l16  = lane & 15;
    const int wm   = (wave >> 1) * 64;
    const int wn   = (wave & 1) * 64;

    const long tile_m = (long)blockIdx.y * 128;
    const long tile_n = (long)blockIdx.x * 128;
    const int  bz     = blockIdx.z;

    const short* pA = A + (long)bz * sA;
    const short* pB = B + (long)bz * sB;

    const int srow = tid >> 2;
    const int skq  = (tid & 3) * 8;
    const int lds_off = srow * 32 + skq;
    const long ga0 = (tile_m + srow) * (long)lda + skq;
    const long gb0 = (tile_n + srow) * (long)ldb + skq;

    auto stage = [&](int k0, int buf) {
        short* s   = smem + buf * SET;
        short* ash = s;
        short* bsh = s + 128 * 32;
        gload_lds16(pA + ga0 + k0,             ash + lds_off);
        gload_lds16(pA + ga0 + 64l * lda + k0, ash + lds_off + 64 * 32);
        gload_lds16(pB + gb0 + k0,             bsh + lds_off);
        gload_lds16(pB + gb0 + 64l * ldb + k0, bsh + lds_off + 64 * 32);
    };

    f32x4 acc[4][4] = {};
    f32x4 oacc[4][4] = {};
    const f32x4 vzero = {0.f, 0.f, 0.f, 0.f};
    stage(0, 0);
    int cur = 0;

    for (int k0 = 0; k0 < K; k0 += 32) {
        __syncthreads();
        if (k0 + 32 < K) stage(k0 + 32, cur ^ 1);

        short* s   = smem + cur * SET;
        short* ash = s;
        short* bsh = s + 128 * 32;

        short8 ah[4], bh[4];
#pragma unroll
        for (int i = 0; i < 4; i++) {
            ah[i] = *(const short8*)&ash[(wm + i * 16 + l16) * 32 + quad * 8];
            bh[i] = *(const short8*)&bsh[(wn + i * 16 + l16) * 32 + quad * 8];
        }
#pragma unroll
        for (int i = 0; i < 4; i++)
#pragma unroll
            for (int j = 0; j < 4; j++)
                acc[i][j] = __builtin_amdgcn_mfma_f32_16x16x32_bf16(ah[i], bh[j], acc[i][j], 0, 0, 0);

        // fold at each 256-k (enc-tile) boundary
        if (((k0 + 32) & 255) == 0) {
            const int tt = k0 >> 8;
#pragma unroll
            for (int i = 0; i < 4; i++) {
                f32x4 sv;
#pragma unroll
                for (int r = 0; r < 4; r++)
                    sv[r] = scales[((long)bz * 2048 + tile_m + wm + i * 16 + quad * 4 + r) * 8 + tt];
#pragma unroll
                for (int j = 0; j < 4; j++) {
                    oacc[i][j] += sv * acc[i][j];
                    acc[i][j] = vzero;
                }
            }
        }
        cur ^= 1;
    }

    // epilogue
#pragma unroll
    for (int i = 0; i < 4; i++)
#pragma unroll
        for (int j = 0; j < 4; j++) {
            const long row0 = tile_m + wm + i * 16 + quad * 4;
            const long col  = tile_n + wn + j * 16 + l16;
#pragma unroll
            for (int r = 0; r < 4; r++)
                C[(long)bz * sC + (row0 + r) * (long)ldc + col] = oacc[i][j][r];
        }
}

// ---------------------------------------------------------------------------
extern "C" void kernel_launch(void* const* d_in, const int* in_sizes, int n_in,
                              void* d_out, int out_size, void* d_ws, size_t ws_size,
                              hipStream_t stream)
{
    const float* enc = (const float*)d_in[0];   // [8,2048,512]
    const float* dec = (const float*)d_in[1];   // [8,2048,512]
    const float* W   = (const float*)d_in[2];   // [512,512]
    float* out = (float*)d_out;                 // [8,2048,512]

    const long BSE = 8l * 2048 * 512;           // 8388608
    const long NW  = 512l * 512;

    char* p = (char*)d_ws;
    auto take = [&](long bytes) { char* r = p; p += (bytes + 255) & ~255l; return r; };
    short* enc_hi = (short*)take(BSE * 2);
    short* enc_lo = (short*)take(BSE * 2);
    short* dec_hi = (short*)take(BSE * 2);
    short* dec_lo = (short*)take(BSE * 2);
    short* ep_hi  = (short*)take(BSE * 2);
    short* ep_lo  = (short*)take(BSE * 2);
    short* enc_t  = (short*)take(BSE * 2);
    short* wt_hi  = (short*)take(NW * 2);
    short* wt_lo  = (short*)take(NW * 2);
    short* Pt     = (short*)take(8l * 2048 * 2048 * 2);   // P~ bf16, 67 MB
    float* stats  = (float*)take(8l * 2048 * 8 * 2 * 4);  // {m,s} per (row,nt)
    float* scales = (float*)take(8l * 2048 * 8 * 4);      // exp(m_t-M)/S
    (void)ws_size; (void)in_sizes; (void)n_in; (void)out_size;

    // one-time: allow 128 KiB dynamic LDS for gemm3_256 (host-side, not a
    // stream op -> graph-capture safe)
    static bool attr_set = false;
    if (!attr_set) {
        (void)hipFuncSetAttribute((const void*)gemm3_256,
                                  hipFuncAttributeMaxDynamicSharedMemorySize,
                                  131072);
        attr_set = true;
    }

    // enc: split + transpose fused (reads enc once)
    split_transpose_kernel<<<dim3(64, 16, 8), 256, 0, stream>>>(
        enc, enc_hi, enc_lo, enc_t);
    split_kernel<<<4096, 256, 0, stream>>>(dec, dec_hi, dec_lo);
    split_w_kernel<<<1024, 256, 0, stream>>>(W, wt_hi, wt_lo);

    // enc_proj = enc @ W  (M=16384, N=512, K=512), 3-term, split bf16 output
    gemm_bt<3, true><<<dim3(4, 128, 1), 256, 64 * 1024, stream>>>(
        enc_hi, enc_lo, wt_hi, wt_lo, nullptr, ep_hi, ep_lo,
        512, 512, 512, 512, 0, 0, 0);

    // logits[b] = dec[b] @ ep[b]^T + fused tile-softmax -> P~, stats
    gemm3_256<<<512, 512, 131072, stream>>>(
        dec_hi, dec_lo, ep_hi, ep_lo, Pt, stats,
        512, 512, 512, 2048l * 512, 2048l * 512, 8, 8);

    // per-row combine -> scales
    combine_kernel<<<64, 256, 0, stream>>>(stats, scales);

    // out[b] = sum_t scale_t * (P~[b] @ enc_t[b])  (M=2048, N=512, K=2048) x 8
    gemm_pv<<<dim3(4, 16, 8), 256, 32 * 1024, stream>>>(
        Pt, enc_t, scales, out,
        2048, 2048, 2048, 512, 2048l * 2048, 512l * 2048, 2048l * 512);
}